// Round 7
// baseline (51.942 us; speedup 1.0000x reference)
//
#include <hip/hip_runtime.h>

#define GSZ   64
#define G3    (GSZ * GSZ * GSZ)      // 262144
#define NCAM  8
#define NJ    23
#define IMW   1280
#define IMH   1024
#define HMW   (IMW / 2)              // 640
#define HMH   (IMH / 2)              // 512
#define HWSZ  (HMW * HMH)            // 327680
#define RMAX  32                     // packed-path cap on distinct runs/wave
#define TMAX  ((RMAX * NJ + 63) / 64)  // 12 packed gather rounds max
#define SSTR  28                     // staging stride: 16B-aligned, bank-spread

__global__ __launch_bounds__(256) void reproj_kernel(
    const float* __restrict__ hm,      // [B, C, J, 512, 640]
    const float* __restrict__ center,  // [B, 3]
    const float* __restrict__ cam,     // [B, C, 4, 3]
    float* __restrict__ out)           // [B, J, 64, 64, 64]
{
#pragma clang fp contract(off)
    const int bid  = blockIdx.x;
    const int b    = bid & 1;                          // batch<->XCD parity
    const int n    = (bid >> 1) * 256 + threadIdx.x;   // z-line waves: lane == z
    const int z = n & 63;
    const int y = (n >> 6) & 63;
    const int x = n >> 12;
    const int lane = threadIdx.x & 63;
    const int wv   = threadIdx.x >> 6;

    __shared__ float sM[NCAM * 12];
    __shared__ int   sOff[4][RMAX];                      // per-wave deduped offsets
    __shared__ __align__(16) float sStage[4][RMAX * SSTR];

    if (threadIdx.x < NCAM * 12) {
        sM[threadIdx.x] = cam[b * NCAM * 12 + threadIdx.x];
    }
    __syncthreads();

    const float cx = center[b * 3 + 0];
    const float cy = center[b * 3 + 1];
    const float cz = center[b * 3 + 2];
    const float px = (float)(x - 32) * 2.0f + cx;
    const float py = (float)(y - 32) * 2.0f + cy;
    const float pz = (float)(z - 32) * 2.0f + cz;

    const float* __restrict__ hmb = hm + (size_t)b * NCAM * NJ * HWSZ;

    // ---- projections + per-camera wave dedup ----
    int off[NCAM], runix[NCAM], Rcnt[NCAM];
    unsigned ldrbits = 0;
#pragma unroll
    for (int c = 0; c < NCAM; ++c) {
        const float* M = &sM[c * 12];
        // XLA/Eigen ordering: sequential FMA along ascending k (bit-exact, R2-verified)
        float p0 = fmaf(pz, M[6], fmaf(py, M[3], px * M[0])) + M[9];
        float p1 = fmaf(pz, M[7], fmaf(py, M[4], px * M[1])) + M[10];
        float p2 = fmaf(pz, M[8], fmaf(py, M[5], px * M[2])) + M[11];
        float u = p0 / p2;              // IEEE divide (no fast-math)
        float v = p1 / p2;
        u = fminf(fmaxf(u, 0.0f), (float)(IMW - 1));
        v = fminf(fmaxf(v, 0.0f), (float)(IMH - 1));
        const int idx = (int)(v * 0.5f) * HMW + (int)(u * 0.5f);
        off[c] = c * (NJ * HWSZ) + idx;

        const int  prev  = __shfl_up(idx, 1);
        const bool start = (lane == 0) || (idx != prev);
        const unsigned long long mask = __ballot(start);
        runix[c] = __popcll(mask & ((2ull << lane) - 1ull)) - 1;
        Rcnt[c]  = __popcll(mask);
        ldrbits |= ((unsigned)start) << c;
    }

    // ---- camera-invariant per-round indices ----
    int rr[TMAX], jHW[TMAX], sAd[TMAX];
#pragma unroll
    for (int t = 0; t < TMAX; ++t) {
        const int p = t * 64 + lane;
        const int r = (int)((unsigned)p / 23u);
        const int j = p - r * 23;
        rr[t]  = r;
        jHW[t] = j * HWSZ;
        sAd[t] = r * SSTR + j;
    }

    float acc[NJ];
#pragma unroll
    for (int j = 0; j < NJ; ++j) acc[j] = 0.0f;

    float vA[TMAX], vB[TMAX];

    // ISSUE: publish deduped offsets, launch packed gathers into V.
    // Fallback (R>RMAX): immediate gather+accumulate (camera order is fp-free:
    // reorder error ~1e-6 << 0.0179 threshold; buckets already bit-exact).
#define PISSUE(c, V)                                                          \
    if (Rcnt[c] <= RMAX) {                                                    \
        if ((ldrbits >> (c)) & 1u) sOff[wv][runix[c]] = off[c];               \
        const int vcnt = Rcnt[c] * NJ;                                        \
        _Pragma("unroll")                                                     \
        for (int t = 0; t < TMAX; ++t) {                                      \
            if (t * 64 + lane < vcnt)                                         \
                V[t] = hmb[sOff[wv][rr[t]] + jHW[t]];                         \
        }                                                                     \
    } else {                                                                  \
        _Pragma("unroll")                                                     \
        for (int j = 0; j < NJ; ++j) acc[j] += hmb[off[c] + j * HWSZ];        \
    }

    // CONSUME: stage V into LDS [run][joint], vectorized readback, accumulate.
#define PCONS(c, V)                                                           \
    if (Rcnt[c] <= RMAX) {                                                    \
        const int vcnt = Rcnt[c] * NJ;                                        \
        _Pragma("unroll")                                                     \
        for (int t = 0; t < TMAX; ++t) {                                      \
            if (t * 64 + lane < vcnt) sStage[wv][sAd[t]] = V[t];              \
        }                                                                     \
        const float* sp = &sStage[wv][runix[c] * SSTR];                       \
        const float4 a0 = ((const float4*)sp)[0];                             \
        const float4 a1 = ((const float4*)sp)[1];                             \
        const float4 a2 = ((const float4*)sp)[2];                             \
        const float4 a3 = ((const float4*)sp)[3];                             \
        const float4 a4 = ((const float4*)sp)[4];                             \
        const float2 a5 = *(const float2*)(sp + 20);                          \
        const float  a6 = sp[22];                                             \
        acc[ 0] += a0.x; acc[ 1] += a0.y; acc[ 2] += a0.z; acc[ 3] += a0.w;   \
        acc[ 4] += a1.x; acc[ 5] += a1.y; acc[ 6] += a1.z; acc[ 7] += a1.w;   \
        acc[ 8] += a2.x; acc[ 9] += a2.y; acc[10] += a2.z; acc[11] += a2.w;   \
        acc[12] += a3.x; acc[13] += a3.y; acc[14] += a3.z; acc[15] += a3.w;   \
        acc[16] += a4.x; acc[17] += a4.y; acc[18] += a4.z; acc[19] += a4.w;   \
        acc[20] += a5.x; acc[21] += a5.y; acc[22] += a6;                      \
    }

    // depth-2 pipeline over cameras: gathers for c+1 in flight during consume of c
    PISSUE(0, vA)
    PISSUE(1, vB)
    PCONS (0, vA)
    PISSUE(2, vA)
    PCONS (1, vB)
    PISSUE(3, vB)
    PCONS (2, vA)
    PISSUE(4, vA)
    PCONS (3, vB)
    PISSUE(5, vB)
    PCONS (4, vA)
    PISSUE(6, vA)
    PCONS (5, vB)
    PISSUE(7, vB)
    PCONS (6, vA)
    PCONS (7, vB)

#undef PISSUE
#undef PCONS

    float* ob = out + (size_t)b * NJ * G3 + n;
#pragma unroll
    for (int j = 0; j < NJ; ++j) {
        ob[(size_t)j * G3] = acc[j] * 0.125f;
    }
}

extern "C" void kernel_launch(void* const* d_in, const int* in_sizes, int n_in,
                              void* d_out, int out_size, void* d_ws, size_t ws_size,
                              hipStream_t stream) {
    const float* hm     = (const float*)d_in[0];
    const float* center = (const float*)d_in[1];
    const float* cam    = (const float*)d_in[2];
    float* out          = (float*)d_out;

    dim3 grid((G3 / 256) * 2, 1, 1);   // (n-chunk, batch) interleaved on bit 0
    dim3 block(256, 1, 1);
    reproj_kernel<<<grid, block, 0, stream>>>(hm, center, cam, out);
}

// Round 8
// 47.806 us; speedup vs baseline: 1.0865x; 1.0865x over previous
//
#include <hip/hip_runtime.h>

#define GSZ   64
#define G3    (GSZ * GSZ * GSZ)      // 262144
#define NCAM  8
#define NJ    23
#define IMW   1280
#define IMH   1024
#define HMW   (IMW / 2)              // 640
#define HMH   (IMH / 2)              // 512
#define HWSZ  (HMW * HMH)            // 327680
#define RMAX  32                     // packed-path cap on distinct runs/wave
#define TMAX  ((RMAX * NJ + 63) / 64)  // 12 packed gather rounds max

__global__ __launch_bounds__(256) void reproj_kernel(
    const float* __restrict__ hm,      // [B, C, J, 512, 640]
    const float* __restrict__ center,  // [B, 3]
    const float* __restrict__ cam,     // [B, C, 4, 3]
    float* __restrict__ out)           // [B, J, 64, 64, 64]
{
#pragma clang fp contract(off)
    const int bid  = blockIdx.x;
    const int b    = bid & 1;                          // batch<->XCD parity
    const int n    = (bid >> 1) * 256 + threadIdx.x;   // z-line waves: lane == z
    const int z = n & 63;
    const int y = (n >> 6) & 63;
    const int x = n >> 12;
    const int lane = threadIdx.x & 63;
    const int wv   = threadIdx.x >> 6;

    __shared__ float sM[NCAM * 12];
    __shared__ int   sOff[4][RMAX];                    // per-wave deduped offsets
    __shared__ __align__(16) float sStage[4][RMAX * 24]; // [run][joint(+pad)]

    if (threadIdx.x < NCAM * 12) {
        sM[threadIdx.x] = cam[b * NCAM * 12 + threadIdx.x];
    }
    __syncthreads();

    const float cx = center[b * 3 + 0];
    const float cy = center[b * 3 + 1];
    const float cz = center[b * 3 + 2];
    const float px = (float)(x - 32) * 2.0f + cx;
    const float py = (float)(y - 32) * 2.0f + cy;
    const float pz = (float)(z - 32) * 2.0f + cz;

    const float* __restrict__ hmb = hm + (size_t)b * NCAM * NJ * HWSZ;

    // ---- projections + per-camera wave dedup ----
    int off[NCAM], runix[NCAM], Rcnt[NCAM];
    unsigned ldrbits = 0;
#pragma unroll
    for (int c = 0; c < NCAM; ++c) {
        const float* M = &sM[c * 12];
        // XLA/Eigen ordering: sequential FMA along ascending k (bit-exact, R2-verified)
        float p0 = fmaf(pz, M[6], fmaf(py, M[3], px * M[0])) + M[9];
        float p1 = fmaf(pz, M[7], fmaf(py, M[4], px * M[1])) + M[10];
        float p2 = fmaf(pz, M[8], fmaf(py, M[5], px * M[2])) + M[11];
        float u = p0 / p2;              // IEEE divide (no fast-math)
        float v = p1 / p2;
        u = fminf(fmaxf(u, 0.0f), (float)(IMW - 1));
        v = fminf(fmaxf(v, 0.0f), (float)(IMH - 1));
        const int idx = (int)(v * 0.5f) * HMW + (int)(u * 0.5f);
        off[c] = c * (NJ * HWSZ) + idx;

        const int  prev  = __shfl_up(idx, 1);
        const bool start = (lane == 0) || (idx != prev);
        const unsigned long long mask = __ballot(start);
        runix[c] = __popcll(mask & ((2ull << lane) - 1ull)) - 1;
        Rcnt[c]  = __popcll(mask);
        ldrbits |= ((unsigned)start) << c;
    }

    // ---- camera-invariant per-round indices ----
    int rr[TMAX], jHW[TMAX], sAd[TMAX];
#pragma unroll
    for (int t = 0; t < TMAX; ++t) {
        const int p = t * 64 + lane;
        const int r = (int)((unsigned)p / 23u);
        const int j = p - r * 23;
        rr[t]  = r;
        jHW[t] = j * HWSZ;
        sAd[t] = r * 24 + j;
    }

    float acc[NJ];
#pragma unroll
    for (int j = 0; j < NJ; ++j) acc[j] = 0.0f;

#pragma unroll
    for (int c = 0; c < NCAM; ++c) {
        const int R     = Rcnt[c];
        const int myrun = runix[c];
        if (R <= RMAX) {
            // leaders publish deduped offsets (same-wave DS ops are in-order)
            if ((ldrbits >> c) & 1u) sOff[wv][myrun] = off[c];
            // wave-uniform round count: scalar branches skip unused rounds
            const int vcnt = __builtin_amdgcn_readfirstlane(R * NJ);

            // A1: fetch round offsets from LDS (all reads issue together)
            int po[TMAX];
#pragma unroll
            for (int t = 0; t < TMAX; ++t) {
                if (t * 64 < vcnt) {                       // uniform skip
                    if (t * 64 + lane < vcnt) po[t] = sOff[wv][rr[t]];
                }
            }
            // A2: packed gathers — all needed rounds issue back-to-back
            float val[TMAX];
#pragma unroll
            for (int t = 0; t < TMAX; ++t) {
                if (t * 64 < vcnt) {                       // uniform skip
                    if (t * 64 + lane < vcnt) val[t] = hmb[po[t] + jHW[t]];
                }
            }
            // B: stage into LDS [run][joint]
#pragma unroll
            for (int t = 0; t < TMAX; ++t) {
                if (t * 64 < vcnt) {                       // uniform skip
                    if (t * 64 + lane < vcnt) sStage[wv][sAd[t]] = val[t];
                }
            }
            // C: vectorized read-back of my run's 23 joints
            const float4* s4 = (const float4*)&sStage[wv][myrun * 24];
            const float4 a0 = s4[0], a1 = s4[1], a2 = s4[2], a3 = s4[3], a4 = s4[4];
            const float2 a5 = *(const float2*)&sStage[wv][myrun * 24 + 20];
            const float  a6 = sStage[wv][myrun * 24 + 22];
            acc[ 0] += a0.x; acc[ 1] += a0.y; acc[ 2] += a0.z; acc[ 3] += a0.w;
            acc[ 4] += a1.x; acc[ 5] += a1.y; acc[ 6] += a1.z; acc[ 7] += a1.w;
            acc[ 8] += a2.x; acc[ 9] += a2.y; acc[10] += a2.z; acc[11] += a2.w;
            acc[12] += a3.x; acc[13] += a3.y; acc[14] += a3.z; acc[15] += a3.w;
            acc[16] += a4.x; acc[17] += a4.y; acc[18] += a4.z; acc[19] += a4.w;
            acc[20] += a5.x; acc[21] += a5.y; acc[22] += a6;
        } else {
            // rare high-diversity wave: plain per-lane gather
            const int o = off[c];
#pragma unroll
            for (int j = 0; j < NJ; ++j) acc[j] += hmb[o + j * HWSZ];
        }
    }

    float* ob = out + (size_t)b * NJ * G3 + n;
#pragma unroll
    for (int j = 0; j < NJ; ++j) {
        ob[(size_t)j * G3] = acc[j] * 0.125f;
    }
}

extern "C" void kernel_launch(void* const* d_in, const int* in_sizes, int n_in,
                              void* d_out, int out_size, void* d_ws, size_t ws_size,
                              hipStream_t stream) {
    const float* hm     = (const float*)d_in[0];
    const float* center = (const float*)d_in[1];
    const float* cam    = (const float*)d_in[2];
    float* out          = (float*)d_out;

    dim3 grid((G3 / 256) * 2, 1, 1);   // (n-chunk, batch) interleaved on bit 0
    dim3 block(256, 1, 1);
    reproj_kernel<<<grid, block, 0, stream>>>(hm, center, cam, out);
}

// Round 9
// 44.485 us; speedup vs baseline: 1.1676x; 1.0747x over previous
//
#include <hip/hip_runtime.h>

#define GSZ   64
#define G3    (GSZ * GSZ * GSZ)      // 262144
#define NCAM  8
#define NJ    23
#define IMW   1280
#define IMH   1024
#define HMW   (IMW / 2)              // 640
#define HMH   (IMH / 2)              // 512
#define HWSZ  (HMW * HMH)            // 327680
#define RMAX  16                     // packed-path cap on distinct runs/wave
#define TMAX  ((RMAX * NJ + 63) / 64)  // 6 packed gather rounds max

__global__ __launch_bounds__(256) void reproj_kernel(
    const float* __restrict__ hm,      // [B, C, J, 512, 640]
    const float* __restrict__ center,  // [B, 3]
    const float* __restrict__ cam,     // [B, C, 4, 3]
    float* __restrict__ out)           // [B, J, 64, 64, 64]
{
#pragma clang fp contract(off)
    const int bid  = blockIdx.x;
    const int b    = bid & 1;                          // batch<->XCD parity
    const int n    = (bid >> 1) * 256 + threadIdx.x;   // z-line waves: lane == z
    const int z = n & 63;
    const int y = (n >> 6) & 63;
    const int x = n >> 12;
    const int lane = threadIdx.x & 63;
    const int wv   = threadIdx.x >> 6;

    __shared__ float sM[NCAM * 12];
    __shared__ int   sOff[4][RMAX];                    // per-wave deduped offsets
    __shared__ __align__(16) float sStage[4][RMAX * 24]; // [run][joint(+pad)]

    if (threadIdx.x < NCAM * 12) {
        sM[threadIdx.x] = cam[b * NCAM * 12 + threadIdx.x];
    }
    __syncthreads();

    const float cx = center[b * 3 + 0];
    const float cy = center[b * 3 + 1];
    const float cz = center[b * 3 + 2];
    const float px = (float)(x - 32) * 2.0f + cx;
    const float py = (float)(y - 32) * 2.0f + cy;
    const float pz = (float)(z - 32) * 2.0f + cz;

    const float* __restrict__ hmb = hm + (size_t)b * NCAM * NJ * HWSZ;

    // ---- projections + per-camera wave dedup ----
    int off[NCAM], runix[NCAM], Rcnt[NCAM];
    unsigned ldrbits = 0;
#pragma unroll
    for (int c = 0; c < NCAM; ++c) {
        const float* M = &sM[c * 12];
        // XLA/Eigen ordering: sequential FMA along ascending k (bit-exact, R2-verified)
        float p0 = fmaf(pz, M[6], fmaf(py, M[3], px * M[0])) + M[9];
        float p1 = fmaf(pz, M[7], fmaf(py, M[4], px * M[1])) + M[10];
        float p2 = fmaf(pz, M[8], fmaf(py, M[5], px * M[2])) + M[11];
        float u = p0 / p2;              // IEEE divide (no fast-math)
        float v = p1 / p2;
        u = fminf(fmaxf(u, 0.0f), (float)(IMW - 1));
        v = fminf(fmaxf(v, 0.0f), (float)(IMH - 1));
        const int idx = (int)(v * 0.5f) * HMW + (int)(u * 0.5f);
        off[c] = c * (NJ * HWSZ) + idx;

        const int  prev  = __shfl_up(idx, 1);
        const bool start = (lane == 0) || (idx != prev);
        const unsigned long long mask = __ballot(start);
        runix[c] = __popcll(mask & ((2ull << lane) - 1ull)) - 1;
        Rcnt[c]  = __popcll(mask);
        ldrbits |= ((unsigned)start) << c;
    }

    // ---- camera-invariant per-round indices ----
    int rr[TMAX], jHW[TMAX], sAd[TMAX];
#pragma unroll
    for (int t = 0; t < TMAX; ++t) {
        const int p = t * 64 + lane;
        const int r = (int)((unsigned)p / 23u);
        const int j = p - r * 23;
        rr[t]  = r;
        jHW[t] = j * HWSZ;
        sAd[t] = r * 24 + j;
    }

    float acc[NJ];
#pragma unroll
    for (int j = 0; j < NJ; ++j) acc[j] = 0.0f;

#pragma unroll
    for (int c = 0; c < NCAM; ++c) {
        const int R     = Rcnt[c];
        const int myrun = runix[c];
        if (R <= RMAX) {
            // leaders publish deduped offsets (same-wave DS ops are in-order)
            if ((ldrbits >> c) & 1u) sOff[wv][myrun] = off[c];
            const int vcnt = R * NJ;

            // A1: fetch round offsets from LDS (all reads issue together)
            int po[TMAX];
#pragma unroll
            for (int t = 0; t < TMAX; ++t) {
                if (t * 64 + lane < vcnt) po[t] = sOff[wv][rr[t]];
            }
            // A2: packed gathers — all 64 lanes fetch distinct (run,joint) values
            float val[TMAX];
#pragma unroll
            for (int t = 0; t < TMAX; ++t) {
                if (t * 64 + lane < vcnt) val[t] = hmb[po[t] + jHW[t]];
            }
            // B: stage into LDS [run][joint]
#pragma unroll
            for (int t = 0; t < TMAX; ++t) {
                if (t * 64 + lane < vcnt) sStage[wv][sAd[t]] = val[t];
            }
            // C: vectorized read-back of my run's 23 joints (6x b128, pad ignored)
            const float4* s4 = (const float4*)&sStage[wv][myrun * 24];
            const float4 a0 = s4[0], a1 = s4[1], a2 = s4[2],
                         a3 = s4[3], a4 = s4[4], a5 = s4[5];
            acc[ 0] += a0.x; acc[ 1] += a0.y; acc[ 2] += a0.z; acc[ 3] += a0.w;
            acc[ 4] += a1.x; acc[ 5] += a1.y; acc[ 6] += a1.z; acc[ 7] += a1.w;
            acc[ 8] += a2.x; acc[ 9] += a2.y; acc[10] += a2.z; acc[11] += a2.w;
            acc[12] += a3.x; acc[13] += a3.y; acc[14] += a3.z; acc[15] += a3.w;
            acc[16] += a4.x; acc[17] += a4.y; acc[18] += a4.z; acc[19] += a4.w;
            acc[20] += a5.x; acc[21] += a5.y; acc[22] += a5.z;
        } else {
            // high-diversity wave: plain per-lane gather
            const int o = off[c];
#pragma unroll
            for (int j = 0; j < NJ; ++j) acc[j] += hmb[o + j * HWSZ];
        }
    }

    float* ob = out + (size_t)b * NJ * G3 + n;
#pragma unroll
    for (int j = 0; j < NJ; ++j) {
        ob[(size_t)j * G3] = acc[j] * 0.125f;
    }
}

extern "C" void kernel_launch(void* const* d_in, const int* in_sizes, int n_in,
                              void* d_out, int out_size, void* d_ws, size_t ws_size,
                              hipStream_t stream) {
    const float* hm     = (const float*)d_in[0];
    const float* center = (const float*)d_in[1];
    const float* cam    = (const float*)d_in[2];
    float* out          = (float*)d_out;

    dim3 grid((G3 / 256) * 2, 1, 1);   // (n-chunk, batch) interleaved on bit 0
    dim3 block(256, 1, 1);
    reproj_kernel<<<grid, block, 0, stream>>>(hm, center, cam, out);
}

// Round 10
// 44.301 us; speedup vs baseline: 1.1725x; 1.0042x over previous
//
#include <hip/hip_runtime.h>

#define GSZ   64
#define G3    (GSZ * GSZ * GSZ)      // 262144
#define NCAM  8
#define NJ    23
#define IMW   1280
#define IMH   1024
#define HMW   (IMW / 2)              // 640
#define HMH   (IMH / 2)              // 512
#define HWSZ  (HMW * HMH)            // 327680
#define RMAX  32                     // packed-path cap on distinct runs/wave
#define RLO   16                     // tier-1 cap: 6 rounds cover R<=16 (16*23=368<=384)
#define TMAX  ((RMAX * NJ + 63) / 64)  // 12 rounds max
#define TLO   ((RLO  * NJ + 63) / 64)  // 6 rounds tier-1

__global__ __launch_bounds__(256) void reproj_kernel(
    const float* __restrict__ hm,      // [B, C, J, 512, 640]
    const float* __restrict__ center,  // [B, 3]
    const float* __restrict__ cam,     // [B, C, 4, 3]
    float* __restrict__ out)           // [B, J, 64, 64, 64]
{
#pragma clang fp contract(off)
    const int bid  = blockIdx.x;
    const int b    = bid & 1;                          // batch<->XCD parity
    const int n    = (bid >> 1) * 256 + threadIdx.x;   // z-line waves: lane == z
    const int z = n & 63;
    const int y = (n >> 6) & 63;
    const int x = n >> 12;
    const int lane = threadIdx.x & 63;
    const int wv   = threadIdx.x >> 6;

    __shared__ float sM[NCAM * 12];
    __shared__ int   sOff[4][RMAX];                    // per-wave deduped offsets
    __shared__ __align__(16) float sStage[4][RMAX * 24]; // [run][joint(+pad)]

    if (threadIdx.x < NCAM * 12) {
        sM[threadIdx.x] = cam[b * NCAM * 12 + threadIdx.x];
    }
    __syncthreads();

    const float cx = center[b * 3 + 0];
    const float cy = center[b * 3 + 1];
    const float cz = center[b * 3 + 2];
    const float px = (float)(x - 32) * 2.0f + cx;
    const float py = (float)(y - 32) * 2.0f + cy;
    const float pz = (float)(z - 32) * 2.0f + cz;

    const float* __restrict__ hmb = hm + (size_t)b * NCAM * NJ * HWSZ;

    // ---- projections + per-camera wave dedup ----
    int off[NCAM], runix[NCAM], Rcnt[NCAM];
    unsigned ldrbits = 0;
#pragma unroll
    for (int c = 0; c < NCAM; ++c) {
        const float* M = &sM[c * 12];
        // XLA/Eigen ordering: sequential FMA along ascending k (bit-exact, R2-verified)
        float p0 = fmaf(pz, M[6], fmaf(py, M[3], px * M[0])) + M[9];
        float p1 = fmaf(pz, M[7], fmaf(py, M[4], px * M[1])) + M[10];
        float p2 = fmaf(pz, M[8], fmaf(py, M[5], px * M[2])) + M[11];
        float u = p0 / p2;              // IEEE divide (no fast-math)
        float v = p1 / p2;
        u = fminf(fmaxf(u, 0.0f), (float)(IMW - 1));
        v = fminf(fmaxf(v, 0.0f), (float)(IMH - 1));
        const int idx = (int)(v * 0.5f) * HMW + (int)(u * 0.5f);
        off[c] = c * (NJ * HWSZ) + idx;

        const int  prev  = __shfl_up(idx, 1);
        const bool start = (lane == 0) || (idx != prev);
        const unsigned long long mask = __ballot(start);
        runix[c] = __popcll(mask & ((2ull << lane) - 1ull)) - 1;
        Rcnt[c]  = __popcll(mask);
        ldrbits |= ((unsigned)start) << c;
    }

    // ---- camera-invariant per-round indices ----
    int rr[TMAX], jHW[TMAX], sAd[TMAX];
#pragma unroll
    for (int t = 0; t < TMAX; ++t) {
        const int p = t * 64 + lane;
        const int r = (int)((unsigned)p / 23u);
        const int j = p - r * 23;
        rr[t]  = r;
        jHW[t] = j * HWSZ;
        sAd[t] = r * 24 + j;
    }

    float acc[NJ];
#pragma unroll
    for (int j = 0; j < NJ; ++j) acc[j] = 0.0f;

#pragma unroll
    for (int c = 0; c < NCAM; ++c) {
        // wave-uniform run count in an SGPR -> scalar branches
        const int Rs    = __builtin_amdgcn_readfirstlane(Rcnt[c]);
        const int myrun = runix[c];
        if (Rs <= RMAX) {
            // leaders publish deduped offsets (same-wave DS ops are in-order)
            if ((ldrbits >> c) & 1u) sOff[wv][myrun] = off[c];
            const int  vcnt = Rs * NJ;
            const bool big  = Rs > RLO;     // scalar: tier-2 rounds needed?

            // A1: fetch round offsets from LDS (tier-1 batch, then tier-2)
            int po[TMAX];
#pragma unroll
            for (int t = 0; t < TLO; ++t) {
                if (t * 64 + lane < vcnt) po[t] = sOff[wv][rr[t]];
            }
            if (big) {
#pragma unroll
                for (int t = TLO; t < TMAX; ++t) {
                    if (t * 64 + lane < vcnt) po[t] = sOff[wv][rr[t]];
                }
            }
            // A2: packed gathers
            float val[TMAX];
#pragma unroll
            for (int t = 0; t < TLO; ++t) {
                if (t * 64 + lane < vcnt) val[t] = hmb[po[t] + jHW[t]];
            }
            if (big) {
#pragma unroll
                for (int t = TLO; t < TMAX; ++t) {
                    if (t * 64 + lane < vcnt) val[t] = hmb[po[t] + jHW[t]];
                }
            }
            // B: stage into LDS [run][joint]
#pragma unroll
            for (int t = 0; t < TLO; ++t) {
                if (t * 64 + lane < vcnt) sStage[wv][sAd[t]] = val[t];
            }
            if (big) {
#pragma unroll
                for (int t = TLO; t < TMAX; ++t) {
                    if (t * 64 + lane < vcnt) sStage[wv][sAd[t]] = val[t];
                }
            }
            // C: vectorized read-back of my run's 23 joints (6x b128, pad ignored)
            const float4* s4 = (const float4*)&sStage[wv][myrun * 24];
            const float4 a0 = s4[0], a1 = s4[1], a2 = s4[2],
                         a3 = s4[3], a4 = s4[4], a5 = s4[5];
            acc[ 0] += a0.x; acc[ 1] += a0.y; acc[ 2] += a0.z; acc[ 3] += a0.w;
            acc[ 4] += a1.x; acc[ 5] += a1.y; acc[ 6] += a1.z; acc[ 7] += a1.w;
            acc[ 8] += a2.x; acc[ 9] += a2.y; acc[10] += a2.z; acc[11] += a2.w;
            acc[12] += a3.x; acc[13] += a3.y; acc[14] += a3.z; acc[15] += a3.w;
            acc[16] += a4.x; acc[17] += a4.y; acc[18] += a4.z; acc[19] += a4.w;
            acc[20] += a5.x; acc[21] += a5.y; acc[22] += a5.z;
        } else {
            // rare very-high-diversity wave: plain per-lane gather
            const int o = off[c];
#pragma unroll
            for (int j = 0; j < NJ; ++j) acc[j] += hmb[o + j * HWSZ];
        }
    }

    float* ob = out + (size_t)b * NJ * G3 + n;
#pragma unroll
    for (int j = 0; j < NJ; ++j) {
        ob[(size_t)j * G3] = acc[j] * 0.125f;
    }
}

extern "C" void kernel_launch(void* const* d_in, const int* in_sizes, int n_in,
                              void* d_out, int out_size, void* d_ws, size_t ws_size,
                              hipStream_t stream) {
    const float* hm     = (const float*)d_in[0];
    const float* center = (const float*)d_in[1];
    const float* cam    = (const float*)d_in[2];
    float* out          = (float*)d_out;

    dim3 grid((G3 / 256) * 2, 1, 1);   // (n-chunk, batch) interleaved on bit 0
    dim3 block(256, 1, 1);
    reproj_kernel<<<grid, block, 0, stream>>>(hm, center, cam, out);
}